// Round 3
// baseline (77.683 us; speedup 1.0000x reference)
//
#include <hip/hip_runtime.h>

typedef float v2f __attribute__((ext_vector_type(2)));
typedef float v4f __attribute__((ext_vector_type(4)));

#define HH 96
#define WW 96
#define NN (HH * WW)            // 9216
#define TILE 1024               // i/j tile size
#define NT (NN / TILE)          // 9 tiles
#define NPAIRS (NT * (NT + 1) / 2)  // 45 tile-pairs (a <= b)
#define JSPLIT 32
#define JC (TILE / JSPLIT)      // 32 j's per block
#define BLK 256
#define M 4                     // i's per thread -> i-tile = M*BLK = 1024

// Gaussian constants with log2(e) folded in (native v_exp_f32 is exp2):
// CXY  = log2(e) / (2 * 15^2),  CRGB = log2(e) / (2 * 0.125^2)
#define CXY 0.0032059890f
#define CRGB 46.16624131f

// arg_ij = (yi,xi,ri,gi,bi,1) . (2CXY*yj, 2CXY*xj, 2CRGB*rj, 2CRGB*gj, 2CRGB*bj, Aj) + Ai
// computed as 3x v_pk_fma_f32 with accumulator seed {0, Ai}, then horizontal add.
// All cross terms >= 0; chain rises from Ai+Aj (>= -392) to <= 0: no overflow.

__device__ __forceinline__ v2f pk_fma(v2f a, v2f b, v2f c) {
    v2f d;
    asm("v_pk_fma_f32 %0, %1, %2, %3" : "=v"(d) : "v"(a), "v"(b), "v"(c));
    return d;
}

__global__ __launch_bounds__(BLK) void crf_pk_kernel(
    const float* __restrict__ probs,   // [2, N], class-0 plane first
    const float* __restrict__ image,   // [3, N]
    float* __restrict__ out)           // [1], pre-zeroed
{
    __shared__ v4f s1[JC];  // (2CXY*yj, 2CXY*xj, 2CRGB*rj, 2CRGB*gj)
    __shared__ v4f s2[JC];  // (2CRGB*bj, Aj, aj, pad)

    // Decode tile-pair (a, b), a <= b, from blockIdx.x (block-uniform scalar loop).
    int p = blockIdx.x;
    int a = 0;
    while (p >= NT - a) { p -= NT - a; ++a; }
    const int b = a + p;

    const int tid = threadIdx.x;

    // Stage the 32-j chunk of tile b into LDS.
    if (tid < JC) {
        const int j  = b * TILE + blockIdx.y * JC + tid;
        const int yj = j / WW;
        const float fy = (float)yj;
        const float fx = (float)(j - yj * WW);
        const float r  = image[j];
        const float g  = image[NN + j];
        const float bl = image[2 * NN + j];
        const float aj = probs[j];
        const float Aj = -CXY * fmaf(fy, fy, fx * fx)
                         - CRGB * fmaf(r, r, fmaf(g, g, bl * bl));
        v4f t1; t1.x = 2.0f * CXY * fy;  t1.y = 2.0f * CXY * fx;
                t1.z = 2.0f * CRGB * r;  t1.w = 2.0f * CRGB * g;
        v4f t2; t2.x = 2.0f * CRGB * bl; t2.y = Aj; t2.z = aj; t2.w = 0.0f;
        s1[tid] = t1;
        s2[tid] = t2;
    }

    // Per-thread i data: M coalesced i's from tile a, packed for v_pk_fma_f32.
    v2f u01[M], u23[M], u45[M], cm[M];
    float ai[M], ci[M], acc[M];
#pragma unroll
    for (int m = 0; m < M; ++m) {
        const int i  = a * TILE + m * BLK + tid;
        const int yy = i / WW;
        const float yi = (float)yy;
        const float xi = (float)(i - yy * WW);
        const float ri = image[i];
        const float gi = image[NN + i];
        const float bi = image[2 * NN + i];
        ai[m] = probs[i];
        ci[m] = fmaf(-2.0f, ai[m], 1.0f);   // 1 - 2*ai
        const float Ai = -CXY * fmaf(yi, yi, xi * xi)
                         - CRGB * fmaf(ri, ri, fmaf(gi, gi, bi * bi));
        u01[m].x = yi; u01[m].y = xi;
        u23[m].x = ri; u23[m].y = gi;
        u45[m].x = bi; u45[m].y = 1.0f;
        cm[m].x = 0.0f; cm[m].y = Ai;
        acc[m] = 0.0f;
    }

    __syncthreads();

#pragma unroll 2
    for (int t = 0; t < JC; ++t) {
        const v4f q1 = s1[t];   // broadcast, conflict-free (ds_read_b128)
        const v4f q2 = s2[t];
        const v2f v01 = q1.xy;  // (vy, vx)
        const v2f v23 = q1.zw;  // (vr, vg)
        const v2f v45 = q2.xy;  // (vb, Aj)
        const float aj = q2.z;
#pragma unroll
        for (int m = 0; m < M; ++m) {
            v2f pp = pk_fma(u01[m], v01, cm[m]);
            pp = pk_fma(u23[m], v23, pp);
            pp = pk_fma(u45[m], v45, pp);
            const float arg = pp.x + pp.y;            // full arg incl. Ai+Aj
            const float k  = __builtin_amdgcn_exp2f(arg);
            const float wv = fmaf(aj, ci[m], ai[m]);  // ai + aj*(1-2ai)
            acc[m] = fmaf(wv, k, acc[m]);
        }
    }

    // Reduce: thread -> wave (64) -> block -> global atomic.
    float s = (acc[0] + acc[1]) + (acc[2] + acc[3]);
    for (int off = 32; off > 0; off >>= 1)
        s += __shfl_down(s, off, 64);

    __shared__ float wsum[BLK / 64];
    if ((tid & 63) == 0) wsum[tid >> 6] = s;
    __syncthreads();
    if (tid == 0) {
        float bs = 0.0f;
#pragma unroll
        for (int w = 0; w < BLK / 64; ++w) bs += wsum[w];
        const float weight = (a == b) ? 1.0f : 2.0f;   // symmetry: off-diag counted twice
        atomicAdd(out, bs * (weight / (float)NN));
    }
}

extern "C" void kernel_launch(void* const* d_in, const int* in_sizes, int n_in,
                              void* d_out, int out_size, void* d_ws, size_t ws_size,
                              hipStream_t stream) {
    const float* probs = (const float*)d_in[0];  // [1,2,96,96] fp32
    const float* image = (const float*)d_in[1];  // [1,3,96,96] fp32
    float* out = (float*)d_out;                  // [1] fp32

    // d_out is poisoned (0xAA) before every timed launch — zero it on-stream.
    hipMemsetAsync(out, 0, sizeof(float), stream);

    dim3 grid(NPAIRS, JSPLIT);   // 45 x 32 = 1440 blocks
    crf_pk_kernel<<<grid, dim3(BLK), 0, stream>>>(probs, image, out);
}

// Round 4
// 76.136 us; speedup vs baseline: 1.0203x; 1.0203x over previous
//
#include <hip/hip_runtime.h>

typedef float v2f __attribute__((ext_vector_type(2)));
typedef float v4f __attribute__((ext_vector_type(4)));

#define HH 96
#define WW 96
#define NN (HH * WW)            // 9216
#define TILE 1024               // i/j tile size
#define NT (NN / TILE)          // 9 tiles
#define NPAIRS (NT * (NT + 1) / 2)  // 45 tile-pairs (a <= b)
#define JSPLIT 32
#define JC (TILE / JSPLIT)      // 32 j's per block -> 16 packed j-pairs
#define BLK 512
#define M 2                     // i's per thread -> i-tile = M*BLK = 1024

// Gaussian constants with log2(e) folded in (native v_exp_f32 is exp2):
// CXY  = log2(e) / (2 * 15^2),  CRGB = log2(e) / (2 * 0.125^2)
#define CXY 0.0032059890f
#define CRGB 46.16624131f

// arg_ij = Ai + Aj + yi*(2CXY*yj) + xi*(2CXY*xj) + ri*(2CRGB*rj) + gi*(2CRGB*gj) + bi*(2CRGB*bj)
// A_k = -CXY*(y^2+x^2) - CRGB*(r^2+g^2+b^2). All cross terms >= 0; the fma chain
// rises monotonically from Ai+Aj (>= -392) to <= 0: no overflow.
// Two j's are packed per float2 lane-pair -> v_pk_fma_f32 via compiler contraction.

struct JPair {          // 64 B: one packed j-pair, b128-aligned
    v4f a;              // (vy0, vy1, vx0, vx1)
    v4f b;              // (vr0, vr1, vg0, vg1)
    v4f c;              // (vb0, vb1, Aj0, Aj1)
    v4f d;              // (aj0, aj1, pad, pad)
};

static __device__ __forceinline__ v2f splat2(float s) { v2f r; r.x = s; r.y = s; return r; }

__global__ __launch_bounds__(BLK, 6) void crf_pkj_kernel(
    const float* __restrict__ probs,   // [2, N], class-0 plane first
    const float* __restrict__ image,   // [3, N]
    float* __restrict__ out)           // [1], pre-zeroed
{
    __shared__ JPair sj[JC / 2];       // 16 pairs = 1 KiB

    // Decode tile-pair (a, b), a <= b, from blockIdx.x (block-uniform scalar loop).
    int p = blockIdx.x;
    int a = 0;
    while (p >= NT - a) { p -= NT - a; ++a; }
    const int b = a + p;

    const int tid = threadIdx.x;

    // Per-thread i data first (overlap global-load latency with staging).
    float yi[M], xi[M], ri[M], gi[M], bi[M], ai[M], ci[M], Ai[M];
    v2f acc[M];
#pragma unroll
    for (int m = 0; m < M; ++m) {
        const int i  = a * TILE + m * BLK + tid;
        const int yy = i / WW;
        yi[m] = (float)yy;
        xi[m] = (float)(i - yy * WW);
        ri[m] = image[i];
        gi[m] = image[NN + i];
        bi[m] = image[2 * NN + i];
        ai[m] = probs[i];
        ci[m] = fmaf(-2.0f, ai[m], 1.0f);   // 1 - 2*ai
        Ai[m] = -CXY * fmaf(yi[m], yi[m], xi[m] * xi[m])
                - CRGB * fmaf(ri[m], ri[m], fmaf(gi[m], gi[m], bi[m] * bi[m]));
        acc[m].x = 0.0f; acc[m].y = 0.0f;
    }

    // Stage the 32-j chunk of tile b into LDS (packed pairs, SoA within struct).
    if (tid < JC) {
        const int j  = b * TILE + blockIdx.y * JC + tid;
        const int yj = j / WW;
        const float fy = (float)yj;
        const float fx = (float)(j - yj * WW);
        const float r  = image[j];
        const float g  = image[NN + j];
        const float bl = image[2 * NN + j];
        const float aj = probs[j];
        const float Aj = -CXY * fmaf(fy, fy, fx * fx)
                         - CRGB * fmaf(r, r, fmaf(g, g, bl * bl));
        float* base = (float*)&sj[tid >> 1];
        const int h = tid & 1;
        base[0  + h] = 2.0f * CXY * fy;
        base[2  + h] = 2.0f * CXY * fx;
        base[4  + h] = 2.0f * CRGB * r;
        base[6  + h] = 2.0f * CRGB * g;
        base[8  + h] = 2.0f * CRGB * bl;
        base[10 + h] = Aj;
        base[12 + h] = aj;
    }

    __syncthreads();

#pragma unroll
    for (int t = 0; t < JC / 2; ++t) {
        const v4f qa = sj[t].a;          // broadcast ds_read_b128 offset:imm
        const v4f qb = sj[t].b;
        const v4f qc = sj[t].c;
        const v2f aj2 = sj[t].d.xy;      // ds_read_b64
        const v2f vy2 = qa.xy, vx2 = qa.zw;
        const v2f vr2 = qb.xy, vg2 = qb.zw;
        const v2f vb2 = qc.xy, Aj2 = qc.zw;
#pragma unroll
        for (int m = 0; m < M; ++m) {
            v2f arg = Aj2 + splat2(Ai[m]);
            arg = vy2 * splat2(yi[m]) + arg;   // -> v_pk_fma_f32
            arg = vx2 * splat2(xi[m]) + arg;
            arg = vr2 * splat2(ri[m]) + arg;
            arg = vg2 * splat2(gi[m]) + arg;
            arg = vb2 * splat2(bi[m]) + arg;
            v2f k2;
            k2.x = __builtin_amdgcn_exp2f(arg.x);
            k2.y = __builtin_amdgcn_exp2f(arg.y);
            const v2f wv = aj2 * splat2(ci[m]) + splat2(ai[m]);  // ai + aj*(1-2ai)
            acc[m] = wv * k2 + acc[m];
        }
    }

    // Reduce: thread -> wave (64) -> block -> global atomic.
    float s = (acc[0].x + acc[0].y) + (acc[1].x + acc[1].y);
    for (int off = 32; off > 0; off >>= 1)
        s += __shfl_down(s, off, 64);

    __shared__ float wsum[BLK / 64];
    if ((tid & 63) == 0) wsum[tid >> 6] = s;
    __syncthreads();
    if (tid == 0) {
        float bs = 0.0f;
#pragma unroll
        for (int w = 0; w < BLK / 64; ++w) bs += wsum[w];
        const float weight = (a == b) ? 1.0f : 2.0f;   // symmetry: off-diag counted twice
        atomicAdd(out, bs * (weight / (float)NN));
    }
}

extern "C" void kernel_launch(void* const* d_in, const int* in_sizes, int n_in,
                              void* d_out, int out_size, void* d_ws, size_t ws_size,
                              hipStream_t stream) {
    const float* probs = (const float*)d_in[0];  // [1,2,96,96] fp32
    const float* image = (const float*)d_in[1];  // [1,3,96,96] fp32
    float* out = (float*)d_out;                  // [1] fp32

    // d_out is poisoned (0xAA) before every timed launch — zero it on-stream.
    hipMemsetAsync(out, 0, sizeof(float), stream);

    dim3 grid(NPAIRS, JSPLIT);   // 45 x 32 = 1440 blocks of 512
    crf_pkj_kernel<<<grid, dim3(BLK), 0, stream>>>(probs, image, out);
}